// Round 3
// baseline (577.501 us; speedup 1.0000x reference)
//
#include <hip/hip_runtime.h>
#include <math.h>

#define DD 128

typedef __attribute__((ext_vector_type(8))) short short8;   // 8 x bf16 bits
typedef __attribute__((ext_vector_type(4))) float f32x4;
typedef __attribute__((ext_vector_type(4))) _Float16 f16x4;

__device__ inline short bf16hi(float x) {
  unsigned u = __float_as_uint(x);
  unsigned r = u + 0x7fffu + ((u >> 16) & 1u);  // RTNE
  return (short)(r >> 16);
}
__device__ inline float bf16tof(short h) {
  return __uint_as_float(((unsigned)(unsigned short)h) << 16);
}
__device__ inline void split2(float x, short& hi, short& lo) {  // RTNE
  hi = bf16hi(x);
  float rem = x - bf16tof(hi);
  lo = bf16hi(rem);
}
__device__ inline void splitT(float x, short& hi, short& lo) {  // truncation (cheap)
  unsigned u = __float_as_uint(x);
  hi = (short)(u >> 16);
  float rem = x - __uint_as_float(u & 0xffff0000u);
  lo = (short)(__float_as_uint(rem) >> 16);
}

// non-temporal stores: keep the 100+MB output streams from evicting the
// L2-resident weight working set (U1F/U2F/WbigF, ~450KB).
__device__ inline void nts(float* p, float v) { __builtin_nontemporal_store(v, p); }
__device__ inline void nts(_Float16* p, _Float16 v) { __builtin_nontemporal_store(v, p); }

// ---------------- small helper kernels ----------------
__global__ __launch_bounds__(128) void zero128_kernel(float* p) { p[threadIdx.x] = 0.f; }

__global__ __launch_bounds__(256) void colsum_kernel(const float* __restrict__ x,
                                                     float* __restrict__ colsum, int N) {
  int col = threadIdx.x & 127;
  int part = (blockIdx.x * blockDim.x + threadIdx.x) >> 7;
  int nparts = (gridDim.x * blockDim.x) >> 7;
  float s = 0.f;
  for (int r = part; r < N; r += nparts) s += x[(size_t)r * DD + col];
  atomicAdd(&colsum[col], s);
}

__global__ __launch_bounds__(128) void glb_kernel(const float* __restrict__ colsum,
                                                  const float* __restrict__ glb_W,
                                                  const float* __restrict__ glb_b,
                                                  float* __restrict__ g, float invN) {
  __shared__ float m[DD];
  int j = threadIdx.x;
  m[j] = colsum[j] * invN;
  __syncthreads();
  float s = glb_b[j];
#pragma unroll 8
  for (int k = 0; k < DD; ++k) s = fmaf(m[k], glb_W[k * DD + j], s);
  g[j] = fmaxf(s, 0.f);
}

// W2U = msg_W2 @ upd_W1[128:256] (128x128), v2 = msg_b2 @ upd_W1[128:256] (128)
__global__ __launch_bounds__(256) void wprep_kernel(const float* __restrict__ msg_W2,
                                                    const float* __restrict__ msg_b2,
                                                    const float* __restrict__ upd_W1,
                                                    float* __restrict__ W2U,
                                                    float* __restrict__ v2) {
  int o = blockIdx.x * 256 + threadIdx.x;
  if (o < 16384) {
    int r = o >> 7, c = o & 127;
    float s = 0.f;
#pragma unroll 8
    for (int j = 0; j < 128; ++j) s = fmaf(msg_W2[r * 128 + j], upd_W1[(128 + j) * 128 + c], s);
    W2U[o] = s;
  } else if (o < 16512) {
    int c = o - 16384;
    float s = 0.f;
#pragma unroll 8
    for (int j = 0; j < 128; ++j) s = fmaf(msg_b2[j], upd_W1[(128 + j) * 128 + c], s);
    v2[c] = s;
  }
}

// ---------------- CSR build: histogram -> parallel scan -> scatter ----------------
__global__ __launch_bounds__(256) void hist_kernel(const int* __restrict__ dst,
                                                   int* __restrict__ rowptr, int E) {
  for (int e = blockIdx.x * blockDim.x + threadIdx.x; e < E; e += gridDim.x * blockDim.x)
    atomicAdd(&rowptr[dst[e] + 1], 1);
}

__global__ __launch_bounds__(1024) void scan1_kernel(int* __restrict__ a,
                                                     int* __restrict__ bsum, int n) {
  __shared__ int buf[1024];
  const int tid = threadIdx.x;
  int i = blockIdx.x * 1024 + tid;
  buf[tid] = (i < n) ? a[i] : 0;
  __syncthreads();
#pragma unroll
  for (int off = 1; off < 1024; off <<= 1) {
    int t = (tid >= off) ? buf[tid - off] : 0;
    __syncthreads();
    buf[tid] += t;
    __syncthreads();
  }
  if (i < n) a[i] = buf[tid];
  if (tid == 1023) bsum[blockIdx.x] = buf[1023];
}

__global__ __launch_bounds__(1024) void scan2_kernel(int* __restrict__ a, int n) {
  __shared__ int buf[1024];
  const int tid = threadIdx.x;
  buf[tid] = (tid < n) ? a[tid] : 0;
  __syncthreads();
#pragma unroll
  for (int off = 1; off < 1024; off <<= 1) {
    int t = (tid >= off) ? buf[tid - off] : 0;
    __syncthreads();
    buf[tid] += t;
    __syncthreads();
  }
  if (tid < n) a[tid] = buf[tid];
}

__global__ __launch_bounds__(1024) void scan3_kernel(int* __restrict__ a,
                                                     const int* __restrict__ bsum, int n) {
  int b = blockIdx.x + 1;
  int i = b * 1024 + threadIdx.x;
  if (i < n) a[i] += bsum[b - 1];
}

__global__ __launch_bounds__(256) void scatter_kernel(const int* __restrict__ src,
                                                      const int* __restrict__ dst,
                                                      int* __restrict__ cursor,
                                                      int* __restrict__ sortedSrc, int E) {
  for (int e = blockIdx.x * blockDim.x + threadIdx.x; e < E; e += gridDim.x * blockDim.x) {
    int pos = atomicAdd(&cursor[dst[e]], 1);
    sortedSrc[pos] = src[e];
  }
}

// ---------------- weight prep: ALL matrices to MFMA-fragment-major hi/lo ----------
// WbigF : [msg_W1|att_W1] both k-halves, 8t x 32n x {hi,lo} x 64lane x 8j
// U1F   : [upd_W1_top; W2U] (256x128) -> 8t x 8n x {hi,lo} x 64lane x 8j
// U2F   : upd_W2 (128x128)            -> 4t x 8n x {hi,lo} x 64lane x 8j
__global__ __launch_bounds__(256) void conv_kernel(
    const float* __restrict__ msg_W1, const float* __restrict__ att_W1,
    const float* __restrict__ upd_W1, const float* __restrict__ upd_W2,
    const float* __restrict__ W2U,
    short* __restrict__ WbigF, short* __restrict__ U1F, short* __restrict__ U2F) {
  int i = blockIdx.x * 256 + threadIdx.x;  // 0 .. 28671
  if (i < 16384) {
    int lane = i & 63, p = (i >> 6) & 1, n = (i >> 7) & 31, c = i >> 12;
    int col = n * 16 + (lane & 15);
#pragma unroll
    for (int j = 0; j < 8; ++j) {
      int k = c * 32 + ((lane >> 4) & 3) * 8 + j;
      float v;
      if (col < 128)      v = msg_W1[k * 128 + col];
      else if (col < 256) v = att_W1[k * 128 + (col - 128)];
      else if (col < 384) v = msg_W1[(k + 128) * 128 + (col - 256)];
      else                v = att_W1[(k + 128) * 128 + (col - 384)];
      short hi, lo; splitT(v, hi, lo);
      WbigF[(size_t)i * 8 + j] = p ? lo : hi;
    }
  } else if (i < 24576) {
    int u = i - 16384;  // t(3b) n(3b) p(1b) lane(6b)
    int lane = u & 63, p = (u >> 6) & 1, n = (u >> 7) & 7, t = u >> 10;
    int col = n * 16 + (lane & 15);
#pragma unroll
    for (int j = 0; j < 8; ++j) {
      int k = t * 32 + (lane >> 4) * 8 + j;
      float v = (k < 128) ? upd_W1[k * 128 + col] : W2U[(k - 128) * 128 + col];
      short hi, lo; split2(v, hi, lo);
      U1F[(size_t)u * 8 + j] = p ? lo : hi;
    }
  } else {
    int u = i - 24576;  // t(2b) n(3b) p(1b) lane(6b)
    int lane = u & 63, p = (u >> 6) & 1, n = (u >> 7) & 7, t = u >> 10;
    int col = n * 16 + (lane & 15);
#pragma unroll
    for (int j = 0; j < 8; ++j) {
      int k = t * 32 + (lane >> 4) * 8 + j;
      float v = upd_W2[k * 128 + col];
      short hi, lo; split2(v, hi, lo);
      U2F[(size_t)u * 8 + j] = p ? lo : hi;
    }
  }
}

// ---------------- Z-prep GEMM (step 0 only): ----------------
// Zsrc[N x 256] fp16 = h @ Wbig[:,0:256] + [msg_b1|att_b1]
// Zdst[N x 256] fp32 = h @ Wbig[:,256:512]
__global__ __launch_bounds__(256, 2) void zprep_kernel(
    const float* __restrict__ h, const short* __restrict__ WbigF,
    const float* __restrict__ msg_b1, const float* __restrict__ att_b1,
    _Float16* __restrict__ Zsrc, float* __restrict__ Zdst, int N) {
  const int tid = threadIdx.x;
  const int w = tid >> 6;
  const int lane = tid & 63;
  const int m16 = lane & 15, q = lane >> 4;
  const int r0 = blockIdx.x * 32;

  f32x4 acc[2][8];
#pragma unroll
  for (int nt = 0; nt < 8; ++nt) {
    int col = w * 128 + nt * 16 + m16;
    float b = (col < 128) ? msg_b1[col] : ((col < 256) ? att_b1[col - 128] : 0.f);
    acc[0][nt] = (f32x4){b, b, b, b};
    acc[1][nt] = (f32x4){b, b, b, b};
  }

  for (int c = 0; c < 4; ++c) {
    short8 ah[2], al[2];
#pragma unroll
    for (int mt = 0; mt < 2; ++mt) {
      int row = min(r0 + mt * 16 + m16, N - 1);
      const float* p = h + (size_t)row * DD + c * 32 + q * 8;
      float4 v0 = *(const float4*)p;
      float4 v1 = *(const float4*)(p + 4);
      float f[8] = {v0.x, v0.y, v0.z, v0.w, v1.x, v1.y, v1.z, v1.w};
#pragma unroll
      for (int j = 0; j < 8; ++j) { short hi, lo; splitT(f[j], hi, lo); ah[mt][j] = hi; al[mt][j] = lo; }
    }
#pragma unroll
    for (int nt = 0; nt < 8; ++nt) {
      int ng = w * 8 + nt;
      const short* bp = WbigF + ((size_t)((c * 32 + ng) * 2) * 64 + lane) * 8;
      short8 bh = *(const short8*)bp;
      short8 bl = *(const short8*)(bp + 512);
#pragma unroll
      for (int mt = 0; mt < 2; ++mt) {
        acc[mt][nt] = __builtin_amdgcn_mfma_f32_16x16x32_bf16(ah[mt], bh, acc[mt][nt], 0, 0, 0);
        acc[mt][nt] = __builtin_amdgcn_mfma_f32_16x16x32_bf16(al[mt], bh, acc[mt][nt], 0, 0, 0);
        acc[mt][nt] = __builtin_amdgcn_mfma_f32_16x16x32_bf16(ah[mt], bl, acc[mt][nt], 0, 0, 0);
      }
    }
  }

#pragma unroll
  for (int mt = 0; mt < 2; ++mt)
#pragma unroll
    for (int r = 0; r < 4; ++r) {
      int row = r0 + mt * 16 + q * 4 + r;
      if (row < N) {
#pragma unroll
        for (int nt = 0; nt < 8; ++nt) {
          int col = w * 128 + nt * 16 + m16;
          float v = acc[mt][nt][r];
          if (col < 256) nts(&Zsrc[(size_t)row * 256 + col], (_Float16)v);
          else           nts(&Zdst[(size_t)row * 256 + (col - 256)], v);
        }
      }
    }
}

// ---------------- CSR aggregation (no atomics; fp16 src gather) ----------------
__global__ __launch_bounds__(256) void aggcsr_kernel(
    const _Float16* __restrict__ Zsrc, const float* __restrict__ Zdst,
    const int* __restrict__ rowptr, const int* __restrict__ sortedSrc,
    const float* __restrict__ att_W2, const float* __restrict__ att_b2,
    float* __restrict__ aggH, float* __restrict__ aggA, int N) {
  const int node = blockIdx.x * 8 + (threadIdx.x >> 5);
  const int c = threadIdx.x & 31;
  if (node >= N) return;

  const float4 aw = *(const float4*)(att_W2 + 4 * c);
  const float ab2 = att_b2[0];
  const float* Zn = Zdst + (size_t)node * 256;
  const float4 dm = *(const float4*)(Zn + 4 * c);
  const float4 da = *(const float4*)(Zn + 128 + 4 * c);

  float aH0 = 0.f, aH1 = 0.f, aH2 = 0.f, aH3 = 0.f, aA = 0.f;
  const int b = rowptr[node], e = rowptr[node + 1];

  int i = b;
  for (; i + 1 < e; i += 2) {
    int s0 = sortedSrc[i], s1 = sortedSrc[i + 1];
    const _Float16* Z0 = Zsrc + (size_t)s0 * 256 + 4 * c;
    const _Float16* Z1 = Zsrc + (size_t)s1 * 256 + 4 * c;
    f16x4 m0 = *(const f16x4*)Z0, a0 = *(const f16x4*)(Z0 + 128);
    f16x4 m1 = *(const f16x4*)Z1, a1 = *(const f16x4*)(Z1 + 128);

    float h0[4], h1[4];
    h0[0] = fmaxf((float)m0[0] + dm.x, 0.f); h0[1] = fmaxf((float)m0[1] + dm.y, 0.f);
    h0[2] = fmaxf((float)m0[2] + dm.z, 0.f); h0[3] = fmaxf((float)m0[3] + dm.w, 0.f);
    h1[0] = fmaxf((float)m1[0] + dm.x, 0.f); h1[1] = fmaxf((float)m1[1] + dm.y, 0.f);
    h1[2] = fmaxf((float)m1[2] + dm.z, 0.f); h1[3] = fmaxf((float)m1[3] + dm.w, 0.f);

    float p0 = fmaf(fmaxf((float)a0[0] + da.x, 0.f), aw.x,
               fmaf(fmaxf((float)a0[1] + da.y, 0.f), aw.y,
               fmaf(fmaxf((float)a0[2] + da.z, 0.f), aw.z,
                    fmaxf((float)a0[3] + da.w, 0.f) * aw.w)));
    float p1 = fmaf(fmaxf((float)a1[0] + da.x, 0.f), aw.x,
               fmaf(fmaxf((float)a1[1] + da.y, 0.f), aw.y,
               fmaf(fmaxf((float)a1[2] + da.z, 0.f), aw.z,
                    fmaxf((float)a1[3] + da.w, 0.f) * aw.w)));
#pragma unroll
    for (int off = 1; off < 32; off <<= 1) {
      p0 += __shfl_xor(p0, off);
      p1 += __shfl_xor(p1, off);
    }
    float t0 = 1.f / (1.f + expf(-(p0 + ab2)));
    float t1 = 1.f / (1.f + expf(-(p1 + ab2)));
    aA += t0 + t1;
    aH0 = fmaf(t0, h0[0], fmaf(t1, h1[0], aH0));
    aH1 = fmaf(t0, h0[1], fmaf(t1, h1[1], aH1));
    aH2 = fmaf(t0, h0[2], fmaf(t1, h1[2], aH2));
    aH3 = fmaf(t0, h0[3], fmaf(t1, h1[3], aH3));
  }
  if (i < e) {
    int s0 = sortedSrc[i];
    const _Float16* Z0 = Zsrc + (size_t)s0 * 256 + 4 * c;
    f16x4 m0 = *(const f16x4*)Z0, a0 = *(const f16x4*)(Z0 + 128);
    float h00 = fmaxf((float)m0[0] + dm.x, 0.f), h01 = fmaxf((float)m0[1] + dm.y, 0.f);
    float h02 = fmaxf((float)m0[2] + dm.z, 0.f), h03 = fmaxf((float)m0[3] + dm.w, 0.f);
    float p0 = fmaf(fmaxf((float)a0[0] + da.x, 0.f), aw.x,
               fmaf(fmaxf((float)a0[1] + da.y, 0.f), aw.y,
               fmaf(fmaxf((float)a0[2] + da.z, 0.f), aw.z,
                    fmaxf((float)a0[3] + da.w, 0.f) * aw.w)));
#pragma unroll
    for (int off = 1; off < 32; off <<= 1) p0 += __shfl_xor(p0, off);
    float t0 = 1.f / (1.f + expf(-(p0 + ab2)));
    aA += t0;
    aH0 = fmaf(t0, h00, aH0);
    aH1 = fmaf(t0, h01, aH1);
    aH2 = fmaf(t0, h02, aH2);
    aH3 = fmaf(t0, h03, aH3);
  }

  *(float4*)(aggH + (size_t)node * DD + 4 * c) = (float4){aH0, aH1, aH2, aH3};
  if (c == 0) aggA[node] = aA;
}

// ---- B-fragment load/compute macros for the software-pipelined node GEMMs ----
#define LDB(WF, t, h0, BH, BL)                                                    \
  {                                                                               \
    _Pragma("unroll") for (int n_ = 0; n_ < 4; ++n_) {                            \
      const short* bp_ = WF + ((size_t)((((t) * 8 + (h0) * 4 + n_) * 2)) * 64 + lane) * 8; \
      BH[n_] = *(const short8*)bp_;                                               \
      BL[n_] = *(const short8*)(bp_ + 512);                                       \
    }                                                                             \
  }

#define MFMA3(ACC, h0, BH, BL, AH, AL)                                            \
  {                                                                               \
    _Pragma("unroll") for (int n_ = 0; n_ < 4; ++n_) {                            \
      ACC[(h0) * 4 + n_] =                                                        \
          __builtin_amdgcn_mfma_f32_16x16x32_bf16(AH, BH[n_], ACC[(h0) * 4 + n_], 0, 0, 0); \
      ACC[(h0) * 4 + n_] =                                                        \
          __builtin_amdgcn_mfma_f32_16x16x32_bf16(AL, BH[n_], ACC[(h0) * 4 + n_], 0, 0, 0); \
      ACC[(h0) * 4 + n_] =                                                        \
          __builtin_amdgcn_mfma_f32_16x16x32_bf16(AH, BL[n_], ACC[(h0) * 4 + n_], 0, 0, 0); \
    }                                                                             \
  }

#define LDA_U1(t, DH, DL)                                                         \
  {                                                                               \
    const float* base_ = (((t) < 4) ? (rs + (t) * 32) : (rd + ((t) - 4) * 32)) + q * 8; \
    float4 v0_ = *(const float4*)base_;                                           \
    float4 v1_ = *(const float4*)(base_ + 4);                                     \
    float f_[8] = {v0_.x, v0_.y, v0_.z, v0_.w, v1_.x, v1_.y, v1_.z, v1_.w};       \
    _Pragma("unroll") for (int j_ = 0; j_ < 8; ++j_) {                            \
      short hi_, lo_; split2(f_[j_], hi_, lo_); DH[j_] = hi_; DL[j_] = lo_;       \
    }                                                                             \
  }

// ---------------- node update (weights frag-major from global; pipelined) ------
// out = relu(h@U1top + aggH@W2U + aggA (x) v2 + upd_b1) @ U2 + upd_b2 + h + g
// DOZ: additionally compute Zsrc/Zdst = out @ Wbig for this block's 64 rows.
template <int DOZ>
__global__ __launch_bounds__(256, 3) void node_mfma_kernel(
    const float* __restrict__ h, const float* __restrict__ aggH,
    const float* __restrict__ aggA, const float* __restrict__ v2,
    const short* __restrict__ U1F, const short* __restrict__ U2F,
    const float* __restrict__ upd_b1, const float* __restrict__ upd_b2,
    const float* __restrict__ g, float* __restrict__ out, int N,
    const short* __restrict__ WbigF, const float* __restrict__ msg_b1,
    const float* __restrict__ att_b1, _Float16* __restrict__ Zsrc,
    float* __restrict__ Zdst) {
  __shared__ __align__(16) short smem[17408];  // 34816 B: HID hi/lo; OUTs overlay
  short* HIDhi = smem;            // 64 x 136
  short* HIDlo = smem + 8704;

  const int tid = threadIdx.x;
  const int wave = tid >> 6;
  const int lane = tid & 63;
  const int m16 = lane & 15;
  const int q = lane >> 4;

  const int n0 = blockIdx.x * 64;
  const int nA = n0 + wave * 16 + m16;
  const int nAc = min(nA, N - 1);
  const float* rs = h + (size_t)nAc * DD;
  const float* rd = aggH + (size_t)nAc * DD;

  f32x4 acc[8];
#pragma unroll
  for (int n = 0; n < 8; ++n) {
    float b = upd_b1[n * 16 + m16];
    acc[n] = (f32x4){b, b, b, b};
  }

  // ---- GEMM1: 8 t-steps, 2-deep pipelined B (4-col groups), A dbuf ----
  {
    short8 BAh[4], BAl[4], BBh[4], BBl[4];
    short8 ah[2], al[2];
    LDB(U1F, 0, 0, BAh, BAl);
    LDA_U1(0, ah[0], al[0]);
#pragma unroll
    for (int t = 0; t < 8; ++t) {
      LDB(U1F, t, 1, BBh, BBl);
      if (t < 7) LDA_U1(t + 1, ah[(t + 1) & 1], al[(t + 1) & 1]);
      MFMA3(acc, 0, BAh, BAl, ah[t & 1], al[t & 1]);
      if (t < 7) LDB(U1F, t + 1, 0, BAh, BAl);
      MFMA3(acc, 1, BBh, BBl, ah[t & 1], al[t & 1]);
    }
  }

  // fold in aggA (x) v2
  {
    float aAv[4];
#pragma unroll
    for (int r = 0; r < 4; ++r) aAv[r] = aggA[min(n0 + wave * 16 + q * 4 + r, N - 1)];
#pragma unroll
    for (int n = 0; n < 8; ++n) {
      float vv = v2[n * 16 + m16];
#pragma unroll
      for (int r = 0; r < 4; ++r) acc[n][r] = fmaf(aAv[r], vv, acc[n][r]);
    }
  }

  // ReLU + hi/lo split into LDS; rows [wave*16, wave*16+16) -> SAME-WAVE only,
  // so no barrier is needed around the transpose.
#pragma unroll
  for (int n = 0; n < 8; ++n) {
    int col = n * 16 + m16;
#pragma unroll
    for (int r = 0; r < 4; ++r) {
      int row = wave * 16 + q * 4 + r;
      float v = fmaxf(acc[n][r], 0.f);
      short hi, lo; split2(v, hi, lo);
      HIDhi[row * 136 + col] = hi;
      HIDlo[row * 136 + col] = lo;
    }
  }

  short8 a2h[4], a2l[4];
  {
    int mrow = wave * 16 + m16;
#pragma unroll
    for (int t = 0; t < 4; ++t) {
      a2h[t] = *(const short8*)(HIDhi + mrow * 136 + t * 32 + q * 8);
      a2l[t] = *(const short8*)(HIDlo + mrow * 136 + t * 32 + q * 8);
    }
  }

  f32x4 acc2[8];
#pragma unroll
  for (int n = 0; n < 8; ++n) {
    float b = upd_b2[n * 16 + m16];
    acc2[n] = (f32x4){b, b, b, b};
  }

  // ---- GEMM2: 4 t-steps, same 2-deep pipelined B ----
  {
    short8 BAh[4], BAl[4], BBh[4], BBl[4];
    LDB(U2F, 0, 0, BAh, BAl);
#pragma unroll
    for (int t = 0; t < 4; ++t) {
      LDB(U2F, t, 1, BBh, BBl);
      MFMA3(acc2, 0, BAh, BAl, a2h[t], a2l[t]);
      if (t < 3) LDB(U2F, t + 1, 0, BAh, BAl);
      MFMA3(acc2, 1, BBh, BBl, a2h[t], a2l[t]);
    }
  }

  // epilogue: out = acc2 + h + g  (also stage into LDS for fused Z-prep)
  float* OUTs = (float*)smem;  // 64 x 132 fp32 overlay (33792 B <= 34816 B)
  if (DOZ) __syncthreads();    // all waves' HID reads done before overlay
#pragma unroll
  for (int r = 0; r < 4; ++r) {
    int rowN = n0 + wave * 16 + q * 4 + r;
    int rc = min(rowN, N - 1);
#pragma unroll
    for (int n = 0; n < 8; ++n) {
      int col = n * 16 + m16;
      float v = acc2[n][r] + h[(size_t)rc * DD + col] + g[col];
      if (DOZ) OUTs[(wave * 16 + q * 4 + r) * 132 + col] = v;
      if (rowN < N) nts(&out[(size_t)rowN * DD + col], v);
    }
  }

  if (DOZ) {
    __syncthreads();
    // Z-GEMM for this block's 64 rows: wave w -> cols [128w, 128w+128)
#pragma unroll
    for (int half = 0; half < 2; ++half) {
      f32x4 zacc[4][4];
#pragma unroll
      for (int nt = 0; nt < 4; ++nt) {
        int col = wave * 128 + half * 64 + nt * 16 + m16;
        float b = (col < 128) ? msg_b1[col] : ((col < 256) ? att_b1[col - 128] : 0.f);
#pragma unroll
        for (int mt = 0; mt < 4; ++mt) zacc[mt][nt] = (f32x4){b, b, b, b};
      }
      for (int c = 0; c < 4; ++c) {
        short8 ah[4], al[4];
#pragma unroll
        for (int mt = 0; mt < 4; ++mt) {
          const float* p = OUTs + (mt * 16 + m16) * 132 + c * 32 + q * 8;
          float4 v0 = *(const float4*)p;
          float4 v1 = *(const float4*)(p + 4);
          float f[8] = {v0.x, v0.y, v0.z, v0.w, v1.x, v1.y, v1.z, v1.w};
#pragma unroll
          for (int j = 0; j < 8; ++j) {
            short hi, lo; splitT(f[j], hi, lo); ah[mt][j] = hi; al[mt][j] = lo;
          }
        }
#pragma unroll
        for (int nt = 0; nt < 4; ++nt) {
          int ng = wave * 8 + half * 4 + nt;
          const short* bp = WbigF + ((size_t)((c * 32 + ng) * 2) * 64 + lane) * 8;
          short8 bh = *(const short8*)bp;
          short8 bl = *(const short8*)(bp + 512);
#pragma unroll
          for (int mt = 0; mt < 4; ++mt) {
            zacc[mt][nt] = __builtin_amdgcn_mfma_f32_16x16x32_bf16(ah[mt], bh, zacc[mt][nt], 0, 0, 0);
            zacc[mt][nt] = __builtin_amdgcn_mfma_f32_16x16x32_bf16(al[mt], bh, zacc[mt][nt], 0, 0, 0);
            zacc[mt][nt] = __builtin_amdgcn_mfma_f32_16x16x32_bf16(ah[mt], bl, zacc[mt][nt], 0, 0, 0);
          }
        }
      }
#pragma unroll
      for (int mt = 0; mt < 4; ++mt)
#pragma unroll
        for (int r = 0; r < 4; ++r) {
          int row = n0 + mt * 16 + q * 4 + r;
          if (row < N) {
#pragma unroll
            for (int nt = 0; nt < 4; ++nt) {
              int col = wave * 128 + half * 64 + nt * 16 + m16;
              float v = zacc[mt][nt][r];
              if (col < 256) nts(&Zsrc[(size_t)row * 256 + col], (_Float16)v);
              else           nts(&Zdst[(size_t)row * 256 + (col - 256)], v);
            }
          }
        }
    }
  }
}

extern "C" void kernel_launch(void* const* d_in, const int* in_sizes, int n_in,
                              void* d_out, int out_size, void* d_ws, size_t ws_size,
                              hipStream_t stream) {
  const float* x = (const float*)d_in[0];
  const int* ei = (const int*)d_in[1];
  const float* msg_W1 = (const float*)d_in[2];
  const float* msg_b1 = (const float*)d_in[3];
  const float* msg_W2 = (const float*)d_in[4];
  const float* msg_b2 = (const float*)d_in[5];
  const float* upd_W1 = (const float*)d_in[6];
  const float* upd_b1 = (const float*)d_in[7];
  const float* upd_W2 = (const float*)d_in[8];
  const float* upd_b2 = (const float*)d_in[9];
  const float* att_W1 = (const float*)d_in[10];
  const float* att_b1 = (const float*)d_in[11];
  const float* att_W2 = (const float*)d_in[12];
  const float* att_b2 = (const float*)d_in[13];
  const float* glb_W = (const float*)d_in[14];
  const float* glb_b = (const float*)d_in[15];

  const int N = in_sizes[0] / DD;
  const int E = in_sizes[1] / 2;
  const int* src = ei;
  const int* dst = ei + E;

  float* out = (float*)d_out;
  float* aggH = (float*)d_ws;                  // N*128 f32
  float* aggA = aggH + (size_t)N * DD;         // N
  float* colsum = aggA + N;                    // 128
  float* g = colsum + DD;                      // 128
  float* W2U = g + DD;                         // 16384 f32
  float* v2 = W2U + 16384;                     // 128 f32
  short* WbigF = (short*)(v2 + DD);            // 131072 shorts
  short* U1F = WbigF + 131072;                 // 65536 shorts
  short* U2F = U1F + 65536;                    // 32768 shorts
  int* bsum = (int*)(U2F + 32768);             // 64 ints
  int* rowptr = bsum + 64;                     // N+1 ints
  int* sortedSrc = rowptr + ((N + 1 + 3) & ~3);
  _Float16* Zsrc = (_Float16*)(sortedSrc + ((E + 3) & ~3));  // N*256 fp16
  float* Zdst = (float*)(Zsrc + (size_t)N * 256);            // N*256 fp32
  int* cursor = (int*)aggH;                    // overlay during sort phase only

  wprep_kernel<<<65, 256, 0, stream>>>(msg_W2, msg_b2, upd_W1, W2U, v2);
  conv_kernel<<<112, 256, 0, stream>>>(msg_W1, att_W1, upd_W1, upd_W2, W2U,
                                       WbigF, U1F, U2F);
  zero128_kernel<<<1, 128, 0, stream>>>(colsum);
  colsum_kernel<<<256, 256, 0, stream>>>(x, colsum, N);
  glb_kernel<<<1, 128, 0, stream>>>(colsum, glb_W, glb_b, g, 1.0f / (float)N);

  // CSR build (edges identical both steps -> sort once per launch)
  hipMemsetAsync(rowptr, 0, (size_t)(N + 1) * sizeof(int), stream);
  hist_kernel<<<1024, 256, 0, stream>>>(dst, rowptr, E);
  const int nscan = N + 1;
  const int nb = (nscan + 1023) / 1024;
  scan1_kernel<<<nb, 1024, 0, stream>>>(rowptr, bsum, nscan);
  scan2_kernel<<<1, 1024, 0, stream>>>(bsum, nb);
  if (nb > 1) scan3_kernel<<<nb - 1, 1024, 0, stream>>>(rowptr, bsum, nscan);
  hipMemcpyAsync(cursor, rowptr, (size_t)N * sizeof(int), hipMemcpyDeviceToDevice, stream);
  scatter_kernel<<<1024, 256, 0, stream>>>(src, dst, cursor, sortedSrc, E);

  const int zgrid = (N + 31) / 32;
  const int agrid = (N + 7) / 8;
  const int ngrid = (N + 63) / 64;

  // step 0
  zprep_kernel<<<zgrid, 256, 0, stream>>>(x, WbigF, msg_b1, att_b1, Zsrc, Zdst, N);
  aggcsr_kernel<<<agrid, 256, 0, stream>>>(Zsrc, Zdst, rowptr, sortedSrc, att_W2, att_b2,
                                           aggH, aggA, N);
  node_mfma_kernel<1><<<ngrid, 256, 0, stream>>>(x, aggH, aggA, v2, U1F, U2F,
                                                 upd_b1, upd_b2, g, out, N,
                                                 WbigF, msg_b1, att_b1, Zsrc, Zdst);
  // step 1
  aggcsr_kernel<<<agrid, 256, 0, stream>>>(Zsrc, Zdst, rowptr, sortedSrc, att_W2, att_b2,
                                           aggH, aggA, N);
  node_mfma_kernel<0><<<ngrid, 256, 0, stream>>>(out, aggH, aggA, v2, U1F, U2F,
                                                 upd_b1, upd_b2, g, out, N,
                                                 WbigF, msg_b1, att_b1, Zsrc, Zdst);
}

// Round 4
// 515.806 us; speedup vs baseline: 1.1196x; 1.1196x over previous
//
#include <hip/hip_runtime.h>
#include <math.h>

#define DD 128

typedef __attribute__((ext_vector_type(8))) short short8;   // 8 x bf16 bits
typedef __attribute__((ext_vector_type(4))) float f32x4;
typedef __attribute__((ext_vector_type(4))) _Float16 f16x4;

__device__ inline short bf16hi(float x) {
  unsigned u = __float_as_uint(x);
  unsigned r = u + 0x7fffu + ((u >> 16) & 1u);  // RTNE
  return (short)(r >> 16);
}
__device__ inline float bf16tof(short h) {
  return __uint_as_float(((unsigned)(unsigned short)h) << 16);
}
__device__ inline void split2(float x, short& hi, short& lo) {  // RTNE
  hi = bf16hi(x);
  float rem = x - bf16tof(hi);
  lo = bf16hi(rem);
}
__device__ inline void splitT(float x, short& hi, short& lo) {  // truncation (cheap)
  unsigned u = __float_as_uint(x);
  hi = (short)(u >> 16);
  float rem = x - __uint_as_float(u & 0xffff0000u);
  lo = (short)(__float_as_uint(rem) >> 16);
}

// async global->LDS, 16B per lane; LDS dest is wave-uniform base + lane*16.
__device__ inline void gload_lds16(const void* g, void* l) {
  __builtin_amdgcn_global_load_lds((const __attribute__((address_space(1))) unsigned*)g,
                                   (__attribute__((address_space(3))) unsigned*)l, 16, 0, 0);
}

// ---------------- small helper kernels ----------------
__global__ __launch_bounds__(128) void zero128_kernel(float* p) { p[threadIdx.x] = 0.f; }

__global__ __launch_bounds__(256) void colsum_kernel(const float* __restrict__ x,
                                                     float* __restrict__ colsum, int N) {
  int col = threadIdx.x & 127;
  int part = (blockIdx.x * blockDim.x + threadIdx.x) >> 7;
  int nparts = (gridDim.x * blockDim.x) >> 7;
  float s = 0.f;
  for (int r = part; r < N; r += nparts) s += x[(size_t)r * DD + col];
  atomicAdd(&colsum[col], s);
}

__global__ __launch_bounds__(128) void glb_kernel(const float* __restrict__ colsum,
                                                  const float* __restrict__ glb_W,
                                                  const float* __restrict__ glb_b,
                                                  float* __restrict__ g, float invN) {
  __shared__ float m[DD];
  int j = threadIdx.x;
  m[j] = colsum[j] * invN;
  __syncthreads();
  float s = glb_b[j];
#pragma unroll 8
  for (int k = 0; k < DD; ++k) s = fmaf(m[k], glb_W[k * DD + j], s);
  g[j] = fmaxf(s, 0.f);
}

// W2U = msg_W2 @ upd_W1[128:256] (128x128), v2 = msg_b2 @ upd_W1[128:256] (128)
__global__ __launch_bounds__(256) void wprep_kernel(const float* __restrict__ msg_W2,
                                                    const float* __restrict__ msg_b2,
                                                    const float* __restrict__ upd_W1,
                                                    float* __restrict__ W2U,
                                                    float* __restrict__ v2) {
  int o = blockIdx.x * 256 + threadIdx.x;
  if (o < 16384) {
    int r = o >> 7, c = o & 127;
    float s = 0.f;
#pragma unroll 8
    for (int j = 0; j < 128; ++j) s = fmaf(msg_W2[r * 128 + j], upd_W1[(128 + j) * 128 + c], s);
    W2U[o] = s;
  } else if (o < 16512) {
    int c = o - 16384;
    float s = 0.f;
#pragma unroll 8
    for (int j = 0; j < 128; ++j) s = fmaf(msg_b2[j], upd_W1[(128 + j) * 128 + c], s);
    v2[c] = s;
  }
}

// ---------------- CSR build: histogram -> parallel scan -> scatter ----------------
__global__ __launch_bounds__(256) void hist_kernel(const int* __restrict__ dst,
                                                   int* __restrict__ rowptr, int E) {
  for (int e = blockIdx.x * blockDim.x + threadIdx.x; e < E; e += gridDim.x * blockDim.x)
    atomicAdd(&rowptr[dst[e] + 1], 1);
}

__global__ __launch_bounds__(1024) void scan1_kernel(int* __restrict__ a,
                                                     int* __restrict__ bsum, int n) {
  __shared__ int buf[1024];
  const int tid = threadIdx.x;
  int i = blockIdx.x * 1024 + tid;
  buf[tid] = (i < n) ? a[i] : 0;
  __syncthreads();
#pragma unroll
  for (int off = 1; off < 1024; off <<= 1) {
    int t = (tid >= off) ? buf[tid - off] : 0;
    __syncthreads();
    buf[tid] += t;
    __syncthreads();
  }
  if (i < n) a[i] = buf[tid];
  if (tid == 1023) bsum[blockIdx.x] = buf[1023];
}

__global__ __launch_bounds__(1024) void scan2_kernel(int* __restrict__ a, int n) {
  __shared__ int buf[1024];
  const int tid = threadIdx.x;
  buf[tid] = (tid < n) ? a[tid] : 0;
  __syncthreads();
#pragma unroll
  for (int off = 1; off < 1024; off <<= 1) {
    int t = (tid >= off) ? buf[tid - off] : 0;
    __syncthreads();
    buf[tid] += t;
    __syncthreads();
  }
  if (tid < n) a[tid] = buf[tid];
}

__global__ __launch_bounds__(1024) void scan3_kernel(int* __restrict__ a,
                                                     const int* __restrict__ bsum, int n) {
  int b = blockIdx.x + 1;
  int i = b * 1024 + threadIdx.x;
  if (i < n) a[i] += bsum[b - 1];
}

__global__ __launch_bounds__(256) void scatter_kernel(const int* __restrict__ src,
                                                      const int* __restrict__ dst,
                                                      int* __restrict__ cursor,
                                                      int* __restrict__ sortedSrc, int E) {
  for (int e = blockIdx.x * blockDim.x + threadIdx.x; e < E; e += gridDim.x * blockDim.x) {
    int pos = atomicAdd(&cursor[dst[e]], 1);
    sortedSrc[pos] = src[e];
  }
}

// ---------------- weight prep: ALL matrices to MFMA-fragment-major hi/lo ----------
// WbigF : [msg_W1|att_W1] both k-halves, 8t x 32n x {hi,lo} x 64lane x 8j
// U1F   : [upd_W1_top; W2U] (256x128) -> 8t x 8n x {hi,lo} x 64lane x 8j
// U2F   : upd_W2 (128x128)            -> 4t x 8n x {hi,lo} x 64lane x 8j
__global__ __launch_bounds__(256) void conv_kernel(
    const float* __restrict__ msg_W1, const float* __restrict__ att_W1,
    const float* __restrict__ upd_W1, const float* __restrict__ upd_W2,
    const float* __restrict__ W2U,
    short* __restrict__ WbigF, short* __restrict__ U1F, short* __restrict__ U2F) {
  int i = blockIdx.x * 256 + threadIdx.x;  // 0 .. 28671
  if (i < 16384) {
    int lane = i & 63, p = (i >> 6) & 1, n = (i >> 7) & 31, c = i >> 12;
    int col = n * 16 + (lane & 15);
#pragma unroll
    for (int j = 0; j < 8; ++j) {
      int k = c * 32 + ((lane >> 4) & 3) * 8 + j;
      float v;
      if (col < 128)      v = msg_W1[k * 128 + col];
      else if (col < 256) v = att_W1[k * 128 + (col - 128)];
      else if (col < 384) v = msg_W1[(k + 128) * 128 + (col - 256)];
      else                v = att_W1[(k + 128) * 128 + (col - 384)];
      short hi, lo; splitT(v, hi, lo);
      WbigF[(size_t)i * 8 + j] = p ? lo : hi;
    }
  } else if (i < 24576) {
    int u = i - 16384;  // t(3b) n(3b) p(1b) lane(6b)
    int lane = u & 63, p = (u >> 6) & 1, n = (u >> 7) & 7, t = u >> 10;
    int col = n * 16 + (lane & 15);
#pragma unroll
    for (int j = 0; j < 8; ++j) {
      int k = t * 32 + (lane >> 4) * 8 + j;
      float v = (k < 128) ? upd_W1[k * 128 + col] : W2U[(k - 128) * 128 + col];
      short hi, lo; split2(v, hi, lo);
      U1F[(size_t)u * 8 + j] = p ? lo : hi;
    }
  } else {
    int u = i - 24576;  // t(2b) n(3b) p(1b) lane(6b)
    int lane = u & 63, p = (u >> 6) & 1, n = (u >> 7) & 7, t = u >> 10;
    int col = n * 16 + (lane & 15);
#pragma unroll
    for (int j = 0; j < 8; ++j) {
      int k = t * 32 + (lane >> 4) * 8 + j;
      float v = upd_W2[k * 128 + col];
      short hi, lo; split2(v, hi, lo);
      U2F[(size_t)u * 8 + j] = p ? lo : hi;
    }
  }
}

// ---------------- Z-prep GEMM (step 0 only): ----------------
// Zsrc[N x 256] fp16 = h @ Wbig[:,0:256] + [msg_b1|att_b1]
// Zdst[N x 256] fp32 = h @ Wbig[:,256:512]
__global__ __launch_bounds__(256, 2) void zprep_kernel(
    const float* __restrict__ h, const short* __restrict__ WbigF,
    const float* __restrict__ msg_b1, const float* __restrict__ att_b1,
    _Float16* __restrict__ Zsrc, float* __restrict__ Zdst, int N) {
  const int tid = threadIdx.x;
  const int w = tid >> 6;
  const int lane = tid & 63;
  const int m16 = lane & 15, q = lane >> 4;
  const int r0 = blockIdx.x * 32;

  f32x4 acc[2][8];
#pragma unroll
  for (int nt = 0; nt < 8; ++nt) {
    int col = w * 128 + nt * 16 + m16;
    float b = (col < 128) ? msg_b1[col] : ((col < 256) ? att_b1[col - 128] : 0.f);
    acc[0][nt] = (f32x4){b, b, b, b};
    acc[1][nt] = (f32x4){b, b, b, b};
  }

  for (int c = 0; c < 4; ++c) {
    short8 ah[2], al[2];
#pragma unroll
    for (int mt = 0; mt < 2; ++mt) {
      int row = min(r0 + mt * 16 + m16, N - 1);
      const float* p = h + (size_t)row * DD + c * 32 + q * 8;
      float4 v0 = *(const float4*)p;
      float4 v1 = *(const float4*)(p + 4);
      float f[8] = {v0.x, v0.y, v0.z, v0.w, v1.x, v1.y, v1.z, v1.w};
#pragma unroll
      for (int j = 0; j < 8; ++j) { short hi, lo; splitT(f[j], hi, lo); ah[mt][j] = hi; al[mt][j] = lo; }
    }
#pragma unroll
    for (int nt = 0; nt < 8; ++nt) {
      int ng = w * 8 + nt;
      const short* bp = WbigF + ((size_t)((c * 32 + ng) * 2) * 64 + lane) * 8;
      short8 bh = *(const short8*)bp;
      short8 bl = *(const short8*)(bp + 512);
#pragma unroll
      for (int mt = 0; mt < 2; ++mt) {
        acc[mt][nt] = __builtin_amdgcn_mfma_f32_16x16x32_bf16(ah[mt], bh, acc[mt][nt], 0, 0, 0);
        acc[mt][nt] = __builtin_amdgcn_mfma_f32_16x16x32_bf16(al[mt], bh, acc[mt][nt], 0, 0, 0);
        acc[mt][nt] = __builtin_amdgcn_mfma_f32_16x16x32_bf16(ah[mt], bl, acc[mt][nt], 0, 0, 0);
      }
    }
  }

#pragma unroll
  for (int mt = 0; mt < 2; ++mt)
#pragma unroll
    for (int r = 0; r < 4; ++r) {
      int row = r0 + mt * 16 + q * 4 + r;
      if (row < N) {
#pragma unroll
        for (int nt = 0; nt < 8; ++nt) {
          int col = w * 128 + nt * 16 + m16;
          float v = acc[mt][nt][r];
          if (col < 256) Zsrc[(size_t)row * 256 + col] = (_Float16)v;
          else           Zdst[(size_t)row * 256 + (col - 256)] = v;
        }
      }
    }
}

// ---------------- CSR aggregation (no atomics; fp16 src gather) ----------------
__global__ __launch_bounds__(256) void aggcsr_kernel(
    const _Float16* __restrict__ Zsrc, const float* __restrict__ Zdst,
    const int* __restrict__ rowptr, const int* __restrict__ sortedSrc,
    const float* __restrict__ att_W2, const float* __restrict__ att_b2,
    float* __restrict__ aggH, float* __restrict__ aggA, int N) {
  const int node = blockIdx.x * 8 + (threadIdx.x >> 5);
  const int c = threadIdx.x & 31;
  if (node >= N) return;

  const float4 aw = *(const float4*)(att_W2 + 4 * c);
  const float ab2 = att_b2[0];
  const float* Zn = Zdst + (size_t)node * 256;
  const float4 dm = *(const float4*)(Zn + 4 * c);
  const float4 da = *(const float4*)(Zn + 128 + 4 * c);

  float aH0 = 0.f, aH1 = 0.f, aH2 = 0.f, aH3 = 0.f, aA = 0.f;
  const int b = rowptr[node], e = rowptr[node + 1];

  int i = b;
  for (; i + 1 < e; i += 2) {
    int s0 = sortedSrc[i], s1 = sortedSrc[i + 1];
    const _Float16* Z0 = Zsrc + (size_t)s0 * 256 + 4 * c;
    const _Float16* Z1 = Zsrc + (size_t)s1 * 256 + 4 * c;
    f16x4 m0 = *(const f16x4*)Z0, a0 = *(const f16x4*)(Z0 + 128);
    f16x4 m1 = *(const f16x4*)Z1, a1 = *(const f16x4*)(Z1 + 128);

    float h0[4], h1[4];
    h0[0] = fmaxf((float)m0[0] + dm.x, 0.f); h0[1] = fmaxf((float)m0[1] + dm.y, 0.f);
    h0[2] = fmaxf((float)m0[2] + dm.z, 0.f); h0[3] = fmaxf((float)m0[3] + dm.w, 0.f);
    h1[0] = fmaxf((float)m1[0] + dm.x, 0.f); h1[1] = fmaxf((float)m1[1] + dm.y, 0.f);
    h1[2] = fmaxf((float)m1[2] + dm.z, 0.f); h1[3] = fmaxf((float)m1[3] + dm.w, 0.f);

    float p0 = fmaf(fmaxf((float)a0[0] + da.x, 0.f), aw.x,
               fmaf(fmaxf((float)a0[1] + da.y, 0.f), aw.y,
               fmaf(fmaxf((float)a0[2] + da.z, 0.f), aw.z,
                    fmaxf((float)a0[3] + da.w, 0.f) * aw.w)));
    float p1 = fmaf(fmaxf((float)a1[0] + da.x, 0.f), aw.x,
               fmaf(fmaxf((float)a1[1] + da.y, 0.f), aw.y,
               fmaf(fmaxf((float)a1[2] + da.z, 0.f), aw.z,
                    fmaxf((float)a1[3] + da.w, 0.f) * aw.w)));
#pragma unroll
    for (int off = 1; off < 32; off <<= 1) {
      p0 += __shfl_xor(p0, off);
      p1 += __shfl_xor(p1, off);
    }
    float t0 = 1.f / (1.f + expf(-(p0 + ab2)));
    float t1 = 1.f / (1.f + expf(-(p1 + ab2)));
    aA += t0 + t1;
    aH0 = fmaf(t0, h0[0], fmaf(t1, h1[0], aH0));
    aH1 = fmaf(t0, h0[1], fmaf(t1, h1[1], aH1));
    aH2 = fmaf(t0, h0[2], fmaf(t1, h1[2], aH2));
    aH3 = fmaf(t0, h0[3], fmaf(t1, h1[3], aH3));
  }
  if (i < e) {
    int s0 = sortedSrc[i];
    const _Float16* Z0 = Zsrc + (size_t)s0 * 256 + 4 * c;
    f16x4 m0 = *(const f16x4*)Z0, a0 = *(const f16x4*)(Z0 + 128);
    float h00 = fmaxf((float)m0[0] + dm.x, 0.f), h01 = fmaxf((float)m0[1] + dm.y, 0.f);
    float h02 = fmaxf((float)m0[2] + dm.z, 0.f), h03 = fmaxf((float)m0[3] + dm.w, 0.f);
    float p0 = fmaf(fmaxf((float)a0[0] + da.x, 0.f), aw.x,
               fmaf(fmaxf((float)a0[1] + da.y, 0.f), aw.y,
               fmaf(fmaxf((float)a0[2] + da.z, 0.f), aw.z,
                    fmaxf((float)a0[3] + da.w, 0.f) * aw.w)));
#pragma unroll
    for (int off = 1; off < 32; off <<= 1) p0 += __shfl_xor(p0, off);
    float t0 = 1.f / (1.f + expf(-(p0 + ab2)));
    aA += t0;
    aH0 = fmaf(t0, h00, aH0);
    aH1 = fmaf(t0, h01, aH1);
    aH2 = fmaf(t0, h02, aH2);
    aH3 = fmaf(t0, h03, aH3);
  }

  *(float4*)(aggH + (size_t)node * DD + 4 * c) = (float4){aH0, aH1, aH2, aH3};
  if (c == 0) aggA[node] = aA;
}

// ---------------- node update: LDS-staged weights via 2-phase gload_lds ring ----
// Weight stream: 24 half-slabs of 8KB. halves 0..15 = U1F (8 t-steps x 2),
// halves 16..23 = U2F (4 t-steps x 2). Ring of two 8KB LDS buffers:
//   stage(i+1) -> compute(i) -> barrier   (loads in flight across compute)
// out = relu(h@U1top + aggH@W2U + aggA (x) v2 + upd_b1) @ U2 + upd_b2 + h + g
// DOZ: additionally compute Zsrc/Zdst = out @ Wbig for this block's 64 rows.
template <int DOZ>
__global__ __launch_bounds__(256, 3) void node_mfma_kernel(
    const float* __restrict__ h, const float* __restrict__ aggH,
    const float* __restrict__ aggA, const float* __restrict__ v2,
    const short* __restrict__ U1F, const short* __restrict__ U2F,
    const float* __restrict__ upd_b1, const float* __restrict__ upd_b2,
    const float* __restrict__ g, float* __restrict__ out, int N,
    const short* __restrict__ WbigF, const float* __restrict__ msg_b1,
    const float* __restrict__ att_b1, _Float16* __restrict__ Zsrc,
    float* __restrict__ Zdst) {
  // 51200 B total -> 3 blocks/CU.
  __shared__ __align__(16) short smem[25600];
  short* WBUF = smem;             // 2 x 4096 shorts (2 x 8KB ring)
  short* HIDhi = smem + 8192;     // 64 x 136
  short* HIDlo = smem + 16896;    // 64 x 136

  const int tid = threadIdx.x;
  const int wave = tid >> 6;
  const int lane = tid & 63;
  const int m16 = lane & 15;
  const int q = lane >> 4;

  const int n0 = blockIdx.x * 64;
  const int nA = n0 + wave * 16 + m16;
  const int nAc = min(nA, N - 1);
  const float* rs = h + (size_t)nAc * DD;
  const float* rd = aggH + (size_t)nAc * DD;

  // stage half-slab i of the unified U1F|U2F stream into ring buffer (i&1)
#define STAGE(i)                                                                   \
  {                                                                                \
    const char* src_ = (const char*)(((i) < 16) ? U1F : U2F) +                     \
                       ((((i) < 16) ? ((i) >> 1) : (((i)-16) >> 1)) * 16384) +     \
                       (((i)&1) * 8192);                                           \
    char* dst_ = (char*)(WBUF + ((i)&1) * 4096);                                   \
    _Pragma("unroll") for (int r_ = 0; r_ < 2; ++r_) {                             \
      gload_lds16(src_ + r_ * 4096 + tid * 16, dst_ + r_ * 4096 + wave * 1024);    \
    }                                                                              \
  }

  // A-fragments for GEMM1 (all 8 t upfront, hi/lo RTNE split)
  short8 a1h[8], a1l[8];
#pragma unroll
  for (int t = 0; t < 8; ++t) {
    const float* base = ((t < 4) ? (rs + t * 32) : (rd + (t - 4) * 32)) + q * 8;
    float4 v0 = *(const float4*)(base);
    float4 v1 = *(const float4*)(base + 4);
    float f[8] = {v0.x, v0.y, v0.z, v0.w, v1.x, v1.y, v1.z, v1.w};
#pragma unroll
    for (int j = 0; j < 8; ++j) { short hi, lo; split2(f[j], hi, lo); a1h[t][j] = hi; a1l[t][j] = lo; }
  }

  f32x4 acc[8];
#pragma unroll
  for (int n = 0; n < 8; ++n) {
    float b = upd_b1[n * 16 + m16];
    acc[n] = (f32x4){b, b, b, b};
  }

  STAGE(0);
  __syncthreads();

  // ---- GEMM1: halves 0..15 ----
#pragma unroll
  for (int i = 0; i < 16; ++i) {
    STAGE(i + 1);  // i==15 stages the first U2F half
    const short* bb = WBUF + (i & 1) * 4096;
    const int t = i >> 1;
#pragma unroll
    for (int n = 0; n < 4; ++n) {
      const short* bp = bb + n * 1024 + lane * 8;
      short8 bh = *(const short8*)bp;
      short8 bl = *(const short8*)(bp + 512);
      const int ng = (i & 1) * 4 + n;
      acc[ng] = __builtin_amdgcn_mfma_f32_16x16x32_bf16(a1h[t], bh, acc[ng], 0, 0, 0);
      acc[ng] = __builtin_amdgcn_mfma_f32_16x16x32_bf16(a1l[t], bh, acc[ng], 0, 0, 0);
      acc[ng] = __builtin_amdgcn_mfma_f32_16x16x32_bf16(a1h[t], bl, acc[ng], 0, 0, 0);
    }
    __syncthreads();
  }

  // fold in aggA (x) v2
  {
    float aAv[4];
#pragma unroll
    for (int r = 0; r < 4; ++r) aAv[r] = aggA[min(n0 + wave * 16 + q * 4 + r, N - 1)];
#pragma unroll
    for (int n = 0; n < 8; ++n) {
      float vv = v2[n * 16 + m16];
#pragma unroll
      for (int r = 0; r < 4; ++r) acc[n][r] = fmaf(aAv[r], vv, acc[n][r]);
    }
  }

  // ReLU + hi/lo split into LDS; rows [wave*16, wave*16+16) are SAME-WAVE only,
  // so no barrier is needed around this transpose.
#pragma unroll
  for (int n = 0; n < 8; ++n) {
    int col = n * 16 + m16;
#pragma unroll
    for (int r = 0; r < 4; ++r) {
      int row = wave * 16 + q * 4 + r;
      float v = fmaxf(acc[n][r], 0.f);
      short hi, lo; split2(v, hi, lo);
      HIDhi[row * 136 + col] = hi;
      HIDlo[row * 136 + col] = lo;
    }
  }

  short8 a2h[4], a2l[4];
  {
    int mrow = wave * 16 + m16;
#pragma unroll
    for (int t = 0; t < 4; ++t) {
      a2h[t] = *(const short8*)(HIDhi + mrow * 136 + t * 32 + q * 8);
      a2l[t] = *(const short8*)(HIDlo + mrow * 136 + t * 32 + q * 8);
    }
  }

  f32x4 acc2[8];
#pragma unroll
  for (int n = 0; n < 8; ++n) {
    float b = upd_b2[n * 16 + m16];
    acc2[n] = (f32x4){b, b, b, b};
  }

  // ---- GEMM2: halves 16..23 (half 16 already staged during GEMM1's tail) ----
#pragma unroll
  for (int i = 16; i < 24; ++i) {
    if (i < 23) STAGE(i + 1);
    const short* bb = WBUF + (i & 1) * 4096;
    const int t = (i - 16) >> 1;
#pragma unroll
    for (int n = 0; n < 4; ++n) {
      const short* bp = bb + n * 1024 + lane * 8;
      short8 bh = *(const short8*)bp;
      short8 bl = *(const short8*)(bp + 512);
      const int ng = (i & 1) * 4 + n;
      acc2[ng] = __builtin_amdgcn_mfma_f32_16x16x32_bf16(a2h[t], bh, acc2[ng], 0, 0, 0);
      acc2[ng] = __builtin_amdgcn_mfma_f32_16x16x32_bf16(a2l[t], bh, acc2[ng], 0, 0, 0);
      acc2[ng] = __builtin_amdgcn_mfma_f32_16x16x32_bf16(a2h[t], bl, acc2[ng], 0, 0, 0);
    }
    __syncthreads();
  }
#undef STAGE

  // epilogue: out = acc2 + h + g  (also stage into LDS for fused Z-prep)
  float* OUTs = (float*)smem;  // 64 x 132 fp32 overlay (33792 B <= 51200 B)
#pragma unroll
  for (int r = 0; r < 4; ++r) {
    int rowN = n0 + wave * 16 + q * 4 + r;
    int rc = min(rowN, N - 1);
#pragma unroll
    for (int n = 0; n < 8; ++n) {
      int col = n * 16 + m16;
      float v = acc2[n][r] + h[(size_t)rc * DD + col] + g[col];
      if (DOZ) OUTs[(wave * 16 + q * 4 + r) * 132 + col] = v;
      if (rowN < N) out[(size_t)rowN * DD + col] = v;
    }
  }

  if (DOZ) {
    __syncthreads();
    // Z-GEMM for this block's 64 rows: wave w -> cols [128w, 128w+128)
#pragma unroll
    for (int half = 0; half < 2; ++half) {
      f32x4 zacc[4][4];
#pragma unroll
      for (int nt = 0; nt < 4; ++nt) {
        int col = wave * 128 + half * 64 + nt * 16 + m16;
        float b = (col < 128) ? msg_b1[col] : ((col < 256) ? att_b1[col - 128] : 0.f);
#pragma unroll
        for (int mt = 0; mt < 4; ++mt) zacc[mt][nt] = (f32x4){b, b, b, b};
      }
      for (int c = 0; c < 4; ++c) {
        short8 ah[4], al[4];
#pragma unroll
        for (int mt = 0; mt < 4; ++mt) {
          const float* p = OUTs + (mt * 16 + m16) * 132 + c * 32 + q * 8;
          float4 v0 = *(const float4*)p;
          float4 v1 = *(const float4*)(p + 4);
          float f[8] = {v0.x, v0.y, v0.z, v0.w, v1.x, v1.y, v1.z, v1.w};
#pragma unroll
          for (int j = 0; j < 8; ++j) {
            short hi, lo; splitT(f[j], hi, lo); ah[mt][j] = hi; al[mt][j] = lo;
          }
        }
#pragma unroll
        for (int nt = 0; nt < 4; ++nt) {
          int ng = wave * 8 + half * 4 + nt;
          const short* bp = WbigF + ((size_t)((c * 32 + ng) * 2) * 64 + lane) * 8;
          short8 bh = *(const short8*)bp;
          short8 bl = *(const short8*)(bp + 512);
#pragma unroll
          for (int mt = 0; mt < 4; ++mt) {
            zacc[mt][nt] = __builtin_amdgcn_mfma_f32_16x16x32_bf16(ah[mt], bh, zacc[mt][nt], 0, 0, 0);
            zacc[mt][nt] = __builtin_amdgcn_mfma_f32_16x16x32_bf16(al[mt], bh, zacc[mt][nt], 0, 0, 0);
            zacc[mt][nt] = __builtin_amdgcn_mfma_f32_16x16x32_bf16(ah[mt], bl, zacc[mt][nt], 0, 0, 0);
          }
        }
      }
#pragma unroll
      for (int mt = 0; mt < 4; ++mt)
#pragma unroll
        for (int r = 0; r < 4; ++r) {
          int row = n0 + mt * 16 + q * 4 + r;
          if (row < N) {
#pragma unroll
            for (int nt = 0; nt < 4; ++nt) {
              int col = wave * 128 + half * 64 + nt * 16 + m16;
              float v = zacc[mt][nt][r];
              if (col < 256) Zsrc[(size_t)row * 256 + col] = (_Float16)v;
              else           Zdst[(size_t)row * 256 + (col - 256)] = v;
            }
          }
        }
    }
  }
}

extern "C" void kernel_launch(void* const* d_in, const int* in_sizes, int n_in,
                              void* d_out, int out_size, void* d_ws, size_t ws_size,
                              hipStream_t stream) {
  const float* x = (const float*)d_in[0];
  const int* ei = (const int*)d_in[1];
  const float* msg_W1 = (const float*)d_in[2];
  const float* msg_b1 = (const float*)d_in[3];
  const float* msg_W2 = (const float*)d_in[4];
  const float* msg_b2 = (const float*)d_in[5];
  const float* upd_W1 = (const float*)d_in[6];
  const float* upd_b1 = (const float*)d_in[7];
  const float* upd_W2 = (const float*)d_in[8];
  const float* upd_b2 = (const float*)d_in[9];
  const float* att_W1 = (const float*)d_in[10];
  const float* att_b1 = (const float*)d_in[11];
  const float* att_W2 = (const float*)d_in[12];
  const float* att_b2 = (const float*)d_in[13];
  const float* glb_W = (const float*)d_in[14];
  const float* glb_b = (const float*)d_in[15];

  const int N = in_sizes[0] / DD;
  const int E = in_sizes[1] / 2;
  const int* src = ei;
  const int* dst = ei + E;

  float* out = (float*)d_out;
  float* aggH = (float*)d_ws;                  // N*128 f32
  float* aggA = aggH + (size_t)N * DD;         // N
  float* colsum = aggA + N;                    // 128
  float* g = colsum + DD;                      // 128
  float* W2U = g + DD;                         // 16384 f32
  float* v2 = W2U + 16384;                     // 128 f32
  short* WbigF = (short*)(v2 + DD);            // 131072 shorts
  short* U1F = WbigF + 131072;                 // 65536 shorts
  short* U2F = U1F + 65536;                    // 32768 shorts
  int* bsum = (int*)(U2F + 32768);             // 64 ints
  int* rowptr = bsum + 64;                     // N+1 ints
  int* sortedSrc = rowptr + ((N + 1 + 3) & ~3);
  _Float16* Zsrc = (_Float16*)(sortedSrc + ((E + 3) & ~3));  // N*256 fp16
  float* Zdst = (float*)(Zsrc + (size_t)N * 256);            // N*256 fp32
  int* cursor = (int*)aggH;                    // overlay during sort phase only

  wprep_kernel<<<65, 256, 0, stream>>>(msg_W2, msg_b2, upd_W1, W2U, v2);
  conv_kernel<<<112, 256, 0, stream>>>(msg_W1, att_W1, upd_W1, upd_W2, W2U,
                                       WbigF, U1F, U2F);
  zero128_kernel<<<1, 128, 0, stream>>>(colsum);
  colsum_kernel<<<256, 256, 0, stream>>>(x, colsum, N);
  glb_kernel<<<1, 128, 0, stream>>>(colsum, glb_W, glb_b, g, 1.0f / (float)N);

  // CSR build (edges identical both steps -> sort once per launch)
  hipMemsetAsync(rowptr, 0, (size_t)(N + 1) * sizeof(int), stream);
  hist_kernel<<<1024, 256, 0, stream>>>(dst, rowptr, E);
  const int nscan = N + 1;
  const int nb = (nscan + 1023) / 1024;
  scan1_kernel<<<nb, 1024, 0, stream>>>(rowptr, bsum, nscan);
  scan2_kernel<<<1, 1024, 0, stream>>>(bsum, nb);
  if (nb > 1) scan3_kernel<<<nb - 1, 1024, 0, stream>>>(rowptr, bsum, nscan);
  hipMemcpyAsync(cursor, rowptr, (size_t)N * sizeof(int), hipMemcpyDeviceToDevice, stream);
  scatter_kernel<<<1024, 256, 0, stream>>>(src, dst, cursor, sortedSrc, E);

  const int zgrid = (N + 31) / 32;
  const int agrid = (N + 7) / 8;
  const int ngrid = (N + 63) / 64;

  // step 0
  zprep_kernel<<<zgrid, 256, 0, stream>>>(x, WbigF, msg_b1, att_b1, Zsrc, Zdst, N);
  aggcsr_kernel<<<agrid, 256, 0, stream>>>(Zsrc, Zdst, rowptr, sortedSrc, att_W2, att_b2,
                                           aggH, aggA, N);
  node_mfma_kernel<1><<<ngrid, 256, 0, stream>>>(x, aggH, aggA, v2, U1F, U2F,
                                                 upd_b1, upd_b2, g, out, N,
                                                 WbigF, msg_b1, att_b1, Zsrc, Zdst);
  // step 1
  aggcsr_kernel<<<agrid, 256, 0, stream>>>(Zsrc, Zdst, rowptr, sortedSrc, att_W2, att_b2,
                                           aggH, aggA, N);
  node_mfma_kernel<0><<<ngrid, 256, 0, stream>>>(out, aggH, aggA, v2, U1F, U2F,
                                                 upd_b1, upd_b2, g, out, N,
                                                 WbigF, msg_b1, att_b1, Zsrc, Zdst);
}